// Round 16
// baseline (651.244 us; speedup 1.0000x reference)
//
#include <hip/hip_runtime.h>

#define IN_C 512
#define HEAD_C 64
#define NHEAD 8
#define TIME_C 256
#define EXPAND_C 2048
#define NB 4
#define NN 2048
#define QKV_DIM 5120   /* 64*8*2 + 512*8 */
#define ROWS (NB*NN)   /* 8192 */
#define MERGE_K (NHEAD*IN_C) /* 4096 */
#define LN2_C (IN_C+TIME_C)  /* 768 */

typedef __bf16 bf16x8 __attribute__((ext_vector_type(8)));
typedef float f32x4 __attribute__((ext_vector_type(4)));
typedef unsigned int u32x4 __attribute__((ext_vector_type(4)));
typedef unsigned short u16x4v __attribute__((ext_vector_type(4)));

__device__ __forceinline__ unsigned short f2bf(float f){
  unsigned int u = __builtin_bit_cast(unsigned int, f);
  u += 0x7fffu + ((u >> 16) & 1u);
  return (unsigned short)(u >> 16);
}
__device__ __forceinline__ unsigned int cvtpk(float a, float b){
  unsigned int r;
  asm("v_cvt_pk_bf16_f32 %0, %1, %2" : "=v"(r) : "v"(a), "v"(b));
  return r;
}
__device__ __forceinline__ float vexp2(float x){   // D = 2^S0
  float r;
  asm("v_exp_f32 %0, %1" : "=v"(r) : "v"(x));
  return r;
}
__device__ __forceinline__ float bpermf(float v, int srclane){
  int r = __builtin_amdgcn_ds_bpermute(srclane<<2, __builtin_bit_cast(int, v));
  return __builtin_bit_cast(float, r);
}
// async global->LDS, 16B per lane; LDS dest is wave-uniform base + lane*16
__device__ __forceinline__ void gload16(const unsigned short* g, unsigned short* l){
  __builtin_amdgcn_global_load_lds(
      (const __attribute__((address_space(1))) void*)g,
      (__attribute__((address_space(3))) void*)l, 16, 0, 0);
}

// ---------------- weight cast + transpose: W[K][N] f32 -> Wt[N][K] bf16 ----------------
__global__ __launch_bounds__(256) void k_transpose_w(const float* __restrict__ W,
                                                     unsigned short* __restrict__ Wt,
                                                     int K, int N){
  __shared__ unsigned short tile[64*72];
  int t = threadIdx.x;
  int kb = blockIdx.y<<6, nb = blockIdx.x<<6;
  {
    int kr = t>>2, nc = (t&3)<<4;
    const float* src = W + (size_t)(kb+kr)*N + nb + nc;
    alignas(16) unsigned short tmp[16];
    #pragma unroll
    for (int j=0;j<16;j+=4){
      float4 v = *(const float4*)(src + j);
      tmp[j+0]=f2bf(v.x); tmp[j+1]=f2bf(v.y); tmp[j+2]=f2bf(v.z); tmp[j+3]=f2bf(v.w);
    }
    *(bf16x8*)&tile[kr*72 + nc]     = *(bf16x8*)&tmp[0];
    *(bf16x8*)&tile[kr*72 + nc + 8] = *(bf16x8*)&tmp[8];
  }
  __syncthreads();
  {
    int nr = t>>2, kc = (t&3)<<4;
    alignas(16) unsigned short ov[16];
    #pragma unroll
    for (int i=0;i<16;i++) ov[i] = tile[(kc+i)*72 + nr];
    unsigned short* dst = Wt + (size_t)(nb+nr)*K + kb + kc;
    *(bf16x8*)dst     = *(bf16x8*)&ov[0];
    *(bf16x8*)(dst+8) = *(bf16x8*)&ov[8];
  }
}

// ---------------- K repack (16x16 A-frags): qkvb K cols -> Kf ----------------
// Frag (bh, kc, g, h): lane l holds K[kc*32 + kappa(g, l&15)][hd = h*32 + (l>>4)*8 + jj]
// kappa(g,p) = (p>>2)*8 + g*4 + (p&3) -> attn P-pack is lane-local, V side identity.
__global__ __launch_bounds__(256) void k_repack_k(const unsigned short* __restrict__ qkv,
                                                  unsigned short* __restrict__ Kf){
  __shared__ unsigned short tile[64*72];
  int j = blockIdx.x;        // 1024 = bh(32) x kb64(32)
  int kb64 = j&31, bh = j>>5;
  int b = bh>>3, hh = bh&7;
  int t = threadIdx.x;
  {
    int key = t>>2, sc = t&3;
    const unsigned short* src = qkv + (size_t)(b*NN + kb64*64 + key)*QKV_DIM + IN_C + hh*HEAD_C;
    *(bf16x8*)&tile[key*72 + sc*8]     = *(const bf16x8*)(src + sc*8);
    *(bf16x8*)&tile[key*72 + (sc+4)*8] = *(const bf16x8*)(src + (sc+4)*8);
  }
  __syncthreads();
  int l = t&63, w = t>>6;
  int kcl = w>>1;
  int p = l&15;
  int hdj = (l>>4)*8;
  #pragma unroll
  for (int i=0;i<2;i++){
    int gh = (w&1)*2 + i;     // g*2+h
    int g = gh>>1, h = gh&1;
    int key = kcl*32 + ((p>>2)*8 + g*4 + (p&3));
    alignas(16) unsigned short ov[8];
    #pragma unroll
    for (int jj=0;jj<8;jj++)
      ov[jj] = tile[key*72 + h*32 + hdj + jj];
    size_t dst = (((size_t)(bh*64 + kb64*2 + kcl))*4 + gh)*512 + l*8;
    *(bf16x8*)(Kf + dst) = *(bf16x8*)ov;
  }
}

// ---------------- V repack (16x16 B-frags): qkvb V cols -> Vf ----------------
// Frag (bh, kc, dt): lane l holds V[kc*32 + (l>>4)*8 + jj][dt*16 + (l&15)]
__global__ __launch_bounds__(256) void k_repack_v(const unsigned short* __restrict__ qkv,
                                                  unsigned short* __restrict__ Vf){
  __shared__ unsigned short tile[64*136];
  int j = blockIdx.x;        // bh(32) x kb64(32)
  int kb64 = j&31, bh = j>>5;
  int b = bh>>3, hh = bh&7;
  int t = threadIdx.x, l = t&63, w = t>>6;
  int key = t>>2, sc = t&3;
  const unsigned short* srow = qkv + (size_t)(b*NN + kb64*64 + key)*QKV_DIM + 2*IN_C + hh*IN_C;
  for (int p=0;p<4;p++){
    #pragma unroll
    for (int i=0;i<4;i++){
      int ch = sc + i*4;
      *(bf16x8*)&tile[key*136 + ch*8] = *(const bf16x8*)(srow + p*128 + ch*8);
    }
    __syncthreads();
    #pragma unroll
    for (int i=0;i<4;i++){
      int f = w*4 + i;          // 0..15
      int kcl = f>>3, dt8 = f&7;
      int dt = p*8 + dt8;
      alignas(16) unsigned short ov[8];
      #pragma unroll
      for (int jj=0;jj<8;jj++)
        ov[jj] = tile[(kcl*32 + (l>>4)*8 + jj)*136 + dt8*16 + (l&15)];
      size_t dst = (((size_t)(bh*64 + kb64*2 + kcl))*32 + dt)*512 + l*8;
      *(bf16x8*)(Vf + dst) = *(bf16x8*)ov;
    }
    __syncthreads();
  }
}

// ---------------- LN1: x[8192][512] f32 -> bf16 ----------------
__global__ __launch_bounds__(256) void k_ln1(const float* __restrict__ x,
                                             const float* __restrict__ g,
                                             const float* __restrict__ bta,
                                             unsigned short* __restrict__ out){
  int row = (blockIdx.x<<2) + (threadIdx.x>>6);
  int l = threadIdx.x&63;
  const float* px = x + (size_t)row*IN_C + l*8;
  alignas(16) float v[8];
  *(float4*)&v[0] = *(const float4*)px;
  *(float4*)&v[4] = *(const float4*)(px+4);
  float s=0.f, sq=0.f;
  #pragma unroll
  for (int j=0;j<8;j++){ s+=v[j]; sq+=v[j]*v[j]; }
  #pragma unroll
  for (int d=32; d>0; d>>=1){ s += __shfl_xor(s,d); sq += __shfl_xor(sq,d); }
  float mu = s*(1.f/IN_C);
  float var = sq*(1.f/IN_C) - mu*mu;
  float rstd = rsqrtf(var + 1e-5f);
  alignas(16) unsigned short o[8];
  #pragma unroll
  for (int j=0;j<8;j++){
    int c = l*8+j;
    o[j] = f2bf((v[j]-mu)*rstd*g[c] + bta[c]);
  }
  *(bf16x8*)(out + (size_t)row*IN_C + l*8) = *(bf16x8*)o;
}

// ---------------- time MLP: tt[b][j] = t[b] @ W + b ----------------
__global__ __launch_bounds__(256) void k_time(const float* __restrict__ t,
                                              const float* __restrict__ W,
                                              const float* __restrict__ bias,
                                              float* __restrict__ tt){
  int b = blockIdx.x, j = threadIdx.x;
  float acc = bias[j];
  const float* tr = t + b*TIME_C;
  #pragma unroll 4
  for (int c=0;c<TIME_C;c++) acc = fmaf(tr[c], W[c*TIME_C + j], acc);
  tt[b*TIME_C + j] = acc;
}

// ---------------- LN2 over concat(x2[512], tt[256]) -> bf16[8192][768], vectorized ----------------
__global__ __launch_bounds__(256) void k_ln2(const float* __restrict__ x2,
                                             const float* __restrict__ tt,
                                             const float* __restrict__ g,
                                             const float* __restrict__ bta,
                                             unsigned short* __restrict__ out){
  int row = (blockIdx.x<<2) + (threadIdx.x>>6);
  int l = threadIdx.x&63;
  int bi = row>>11;
  int c0 = l*12;
  alignas(16) float v[12], gg[12], bb[12];
  #pragma unroll
  for (int q=0;q<3;q++){
    int c = c0 + q*4;
    const float* src = (c < IN_C) ? &x2[(size_t)row*IN_C + c] : &tt[bi*TIME_C + c - IN_C];
    *(float4*)&v[q*4]  = *(const float4*)src;
    *(float4*)&gg[q*4] = *(const float4*)&g[c];
    *(float4*)&bb[q*4] = *(const float4*)&bta[c];
  }
  float s=0.f, sq=0.f;
  #pragma unroll
  for (int j=0;j<12;j++){ s+=v[j]; sq+=v[j]*v[j]; }
  #pragma unroll
  for (int d=32; d>0; d>>=1){ s += __shfl_xor(s,d); sq += __shfl_xor(sq,d); }
  float mu = s*(1.f/LN2_C);
  float var = sq*(1.f/LN2_C) - mu*mu;
  float rstd = rsqrtf(var + 1e-5f);
  alignas(8) unsigned short ov[12];
  #pragma unroll
  for (int j=0;j<12;j++)
    ov[j] = f2bf((v[j]-mu)*rstd*gg[j] + bb[j]);
  unsigned short* po = out + (size_t)row*LN2_C + c0;
  *(u16x4v*)&po[0] = *(u16x4v*)&ov[0];
  *(u16x4v*)&po[4] = *(u16x4v*)&ov[4];
  *(u16x4v*)&po[8] = *(u16x4v*)&ov[8];
}

// ---------------- GEMM (m97 structure): global_load_lds staging, BK=64, BN templated,
// XCD-chunked block swizzle (T1).
template<int EPI, int BN>
__global__ __launch_bounds__(256) void k_gemm(const unsigned short* __restrict__ A, int lda,
                                              const unsigned short* __restrict__ Bt, int ldb,
                                              const float* __restrict__ bias,
                                              const float* __restrict__ res, int ldres,
                                              void* __restrict__ Cp, int ldc, int K){
  constexpr int NI = BN/32;                 // acc cols per wave
  __shared__ unsigned short sA[128*64];
  __shared__ unsigned short sB[BN*64];
  int t = threadIdx.x;
  int l = t&63, w = t>>6;
  // bijective XCD-chunked swizzle (nwg % 8 == 0 for all our launches)
  int nxb = gridDim.x;
  int bid = blockIdx.x + nxb*blockIdx.y;
  int cpx = (nxb*gridDim.y) >> 3;
  int sb  = (bid&7)*cpx + (bid>>3);
  int bx  = sb % nxb, by = sb / nxb;
  int m0 = by<<7, n0 = bx*BN;
  int wr = (w>>1)<<6, wc = (w&1)*(BN/2);
  int lm = l&15, kq = (l>>4)<<3;
  f32x4 acc[4][NI] = {};
  int srow = l>>3, scol = (l&7)<<3;
  const unsigned short* pA = A + (size_t)m0*lda;
  const unsigned short* pB = Bt + (size_t)n0*ldb;
  for (int k0=0; k0<K; k0+=64){
    #pragma unroll
    for (int i=0;i<4;i++){
      int c = w*4 + i;
      gload16(pA + (size_t)(c*8 + srow)*lda + k0 + scol, &sA[c*512]);
    }
    #pragma unroll
    for (int i=0;i<BN/32;i++){
      int c = w*(BN/32) + i;
      gload16(pB + (size_t)(c*8 + srow)*ldb + k0 + scol, &sB[c*512]);
    }
    __syncthreads();                       // vmcnt drained -> tiles ready
    bf16x8 af[2][4], bfv[2][NI];
    #pragma unroll
    for (int kk=0;kk<2;kk++){
      #pragma unroll
      for (int i=0;i<4;i++)
        af[kk][i]  = *(const bf16x8*)&sA[(wr + i*16 + lm)*64 + kk*32 + kq];
      #pragma unroll
      for (int i=0;i<NI;i++)
        bfv[kk][i] = *(const bf16x8*)&sB[(wc + i*16 + lm)*64 + kk*32 + kq];
    }
    #pragma unroll
    for (int kk=0;kk<2;kk++)
      #pragma unroll
      for (int mi=0;mi<4;mi++)
        #pragma unroll
        for (int ni=0;ni<NI;ni++)
          acc[mi][ni] = __builtin_amdgcn_mfma_f32_16x16x32_bf16(af[kk][mi], bfv[kk][ni], acc[mi][ni], 0,0,0);
    __syncthreads();                       // all reads done before next stage
  }
  int lr4 = (l>>4)<<2;
  #pragma unroll
  for (int mi=0;mi<4;mi++){
    int row0 = m0 + wr + mi*16 + lr4;
    #pragma unroll
    for (int ni=0;ni<NI;ni++){
      int col = n0 + wc + ni*16 + lm;
      float bi = bias[col];
      #pragma unroll
      for (int r=0;r<4;r++){
        float v = acc[mi][ni][r] + bi;
        int row = row0 + r;
        if (EPI==1){
          v += res[(size_t)row*ldres + col];
          ((float*)Cp)[(size_t)row*ldc + col] = v;
        } else if (EPI==2){
          v = 0.5f*v*(1.f + erff(v*0.70710678118f));
          ((unsigned short*)Cp)[(size_t)row*ldc + col] = f2bf(v);
        } else {
          ((unsigned short*)Cp)[(size_t)row*ldc + col] = f2bf(v);
        }
      }
    }
  }
}

// ---------------- flash attention v14: 16x16 MFMA, 16q x 256d per wave (dup 2x) ----------------
// 2048 blocks x 256 thr (4 waves). Wave = (bh, 16 q-rows, 256 d-cols dh half).
// QK^T: S1/S2 = mfma16(Kf_g, Qf) with kappa-permuted Kf -> lane l holds P for
// q=l&15, keys (l>>4)*8+0..7 -> pf = cvtpk(pv[0..7]) directly (zero cross-lane),
// V-side identity. PV: 16 mfma16 into o[16] (64 AGPR). exps/QK dup halved vs v13.
__global__ __launch_bounds__(256, 4) void k_attn(const unsigned short* __restrict__ qkv,
                                                 const unsigned short* __restrict__ Kf,
                                                 const unsigned short* __restrict__ Vf,
                                                 unsigned short* __restrict__ out){
  int j = blockIdx.x;
  int xcd = j&7;
  int rest = j>>3;                 // 0..255
  int bh = xcd + ((rest>>6)<<3);   // 4 bh-groups of 8 per XCD
  int inner = rest&63;
  int qs = inner>>1, dh = inner&1;
  int b = bh>>3, hh = bh&7;
  int t = threadIdx.x, l = t&63, w = t>>6;
  int q0 = qs*64 + w*16;
  int lp = l&15, lg = l>>4;

  // Q B-frags, pre-scaled by 0.125*log2(e): lane holds Q[hd=kk*32+lg*8+j][q=q0+lp]
  bf16x8 qf[2];
  #pragma unroll
  for (int kk=0;kk<2;kk++){
    bf16x8 raw = *(const bf16x8*)(qkv + (size_t)(b*NN + q0 + lp)*QKV_DIM + hh*HEAD_C + kk*32 + lg*8);
    u32x4 u = __builtin_bit_cast(u32x4, raw);
    u32x4 rr;
    #pragma unroll
    for (int jj=0;jj<4;jj++){
      float lo = __builtin_bit_cast(float, (u[jj]&0xffffu)<<16);
      float hi = __builtin_bit_cast(float, u[jj]&0xffff0000u);
      rr[jj] = cvtpk(lo*0.18033688f, hi*0.18033688f);
    }
    qf[kk] = __builtin_bit_cast(bf16x8, rr);
  }

  f32x4 o[16];
  #pragma unroll
  for (int i=0;i<16;i++) o[i] = (f32x4){0.f,0.f,0.f,0.f};
  float l_ = 0.f;                  // partial: this lane's 8 keys per chunk, q=lp

  const unsigned short* Kbase = Kf + (size_t)bh*64*4*512 + l*8;
  const unsigned short* Vbase = Vf + ((size_t)bh*64*32 + dh*16)*512 + l*8;

  for (int c=0;c<64;c++){
    const unsigned short* kp = Kbase + (size_t)c*4*512;
    bf16x8 kf0 = *(const bf16x8*)(kp);
    bf16x8 kf1 = *(const bf16x8*)(kp + 512);
    bf16x8 kf2 = *(const bf16x8*)(kp + 1024);
    bf16x8 kf3 = *(const bf16x8*)(kp + 1536);

    f32x4 s1 = {0.f,0.f,0.f,0.f}, s2 = {0.f,0.f,0.f,0.f};
    s1 = __builtin_amdgcn_mfma_f32_16x16x32_bf16(kf0, qf[0], s1, 0,0,0);
    s1 = __builtin_amdgcn_mfma_f32_16x16x32_bf16(kf1, qf[1], s1, 0,0,0);
    s2 = __builtin_amdgcn_mfma_f32_16x16x32_bf16(kf2, qf[0], s2, 0,0,0);
    s2 = __builtin_amdgcn_mfma_f32_16x16x32_bf16(kf3, qf[1], s2, 0,0,0);

    float pv[8];
    pv[0]=vexp2(s1[0]); pv[1]=vexp2(s1[1]); pv[2]=vexp2(s1[2]); pv[3]=vexp2(s1[3]);
    pv[4]=vexp2(s2[0]); pv[5]=vexp2(s2[1]); pv[6]=vexp2(s2[2]); pv[7]=vexp2(s2[3]);
    l_ += ((pv[0]+pv[1])+(pv[2]+pv[3])) + ((pv[4]+pv[5])+(pv[6]+pv[7]));

    bf16x8 pf = __builtin_bit_cast(bf16x8, (u32x4){ cvtpk(pv[0],pv[1]), cvtpk(pv[2],pv[3]),
                                                    cvtpk(pv[4],pv[5]), cvtpk(pv[6],pv[7]) });

    const unsigned short* vp = Vbase + (size_t)c*32*512;
    #pragma unroll
    for (int dq=0;dq<4;dq++){
      bf16x8 v0 = *(const bf16x8*)(vp + (dq*4+0)*512);
      bf16x8 v1 = *(const bf16x8*)(vp + (dq*4+1)*512);
      bf16x8 v2 = *(const bf16x8*)(vp + (dq*4+2)*512);
      bf16x8 v3 = *(const bf16x8*)(vp + (dq*4+3)*512);
      o[dq*4+0] = __builtin_amdgcn_mfma_f32_16x16x32_bf16(pf, v0, o[dq*4+0], 0,0,0);
      o[dq*4+1] = __builtin_amdgcn_mfma_f32_16x16x32_bf16(pf, v1, o[dq*4+1], 0,0,0);
      o[dq*4+2] = __builtin_amdgcn_mfma_f32_16x16x32_bf16(pf, v2, o[dq*4+2], 0,0,0);
      o[dq*4+3] = __builtin_amdgcn_mfma_f32_16x16x32_bf16(pf, v3, o[dq*4+3], 0,0,0);
    }
  }

  // complete row sums: lane-groups lg=0..3 hold disjoint key slices for q=lp
  l_ += __shfl_xor(l_, 16);
  l_ += __shfl_xor(l_, 32);
  float invl = 1.f / l_;
  #pragma unroll
  for (int r=0;r<4;r++){
    int qr = lg*4 + r;                       // D row = q
    float il = bpermf(invl, qr);             // lane qr holds q=qr's sum
    size_t row = (size_t)(b*NN + q0 + qr);
    #pragma unroll
    for (int dt=0;dt<16;dt++){
      int col = hh*IN_C + dh*256 + dt*16 + lp;
      out[row*MERGE_K + col] = f2bf(o[dt][r]*il);
    }
  }
}

extern "C" void kernel_launch(void* const* d_in, const int* in_sizes, int n_in,
                              void* d_out, int out_size, void* d_ws, size_t ws_size,
                              hipStream_t stream){
  const float* x       = (const float*)d_in[0];
  const float* tin     = (const float*)d_in[1];
  const float* ln1_g   = (const float*)d_in[2];
  const float* ln1_b   = (const float*)d_in[3];
  const float* qkv_w   = (const float*)d_in[4];
  const float* qkv_b   = (const float*)d_in[5];
  const float* merge_w = (const float*)d_in[6];
  const float* merge_b = (const float*)d_in[7];
  const float* time_w  = (const float*)d_in[8];
  const float* time_b  = (const float*)d_in[9];
  const float* ln2_g   = (const float*)d_in[10];
  const float* ln2_b   = (const float*)d_in[11];
  const float* ff1_w   = (const float*)d_in[12];
  const float* ff1_b   = (const float*)d_in[13];
  const float* ff2_w   = (const float*)d_in[14];
  const float* ff2_b   = (const float*)d_in[15];

  char* ws = (char*)d_ws;
  size_t off = 0;
  auto alloc = [&](size_t bytes)->void*{ void* p = ws + off; off += (bytes + 255) & ~(size_t)255; return p; };
  unsigned short* wqkvT   = (unsigned short*)alloc((size_t)QKV_DIM*IN_C*2);
  unsigned short* wmergeT = (unsigned short*)alloc((size_t)IN_C*MERGE_K*2);
  unsigned short* wff1T   = (unsigned short*)alloc((size_t)EXPAND_C*LN2_C*2);
  unsigned short* wff2T   = (unsigned short*)alloc((size_t)IN_C*EXPAND_C*2);
  float*          ttb     = (float*)alloc((size_t)NB*TIME_C*4);
  unsigned short* ln1o    = (unsigned short*)alloc((size_t)ROWS*IN_C*2);
  unsigned short* qkvb    = (unsigned short*)alloc((size_t)ROWS*QKV_DIM*2);
  unsigned short* kfrag   = (unsigned short*)alloc((size_t)32*64*4*512*2);       // 8 MB
  unsigned short* vfrag   = (unsigned short*)alloc((size_t)32*64*32*512*2);      // 64 MB
  unsigned short* atto    = (unsigned short*)alloc((size_t)ROWS*MERGE_K*2);
  float*          x2      = (float*)alloc((size_t)ROWS*IN_C*4);
  // aliases over dead buffers (lifetimes verified):
  unsigned short* ln2o = vfrag; // vfrag dead after k_attn
  unsigned short* hbuf = qkvb;  // qkvb dead after k_attn

  k_transpose_w<<<dim3(QKV_DIM/64, IN_C/64),  256, 0, stream>>>(qkv_w,   wqkvT,   IN_C,     QKV_DIM);
  k_transpose_w<<<dim3(IN_C/64,   MERGE_K/64),256, 0, stream>>>(merge_w, wmergeT, MERGE_K,  IN_C);
  k_transpose_w<<<dim3(EXPAND_C/64, LN2_C/64),256, 0, stream>>>(ff1_w,   wff1T,   LN2_C,    EXPAND_C);
  k_transpose_w<<<dim3(IN_C/64,   EXPAND_C/64),256, 0, stream>>>(ff2_w,  wff2T,   EXPAND_C, IN_C);
  k_time<<<dim3(NB), 256, 0, stream>>>(tin, time_w, time_b, ttb);
  k_ln1<<<dim3(ROWS/4), 256, 0, stream>>>(x, ln1_g, ln1_b, ln1o);

  k_gemm<0,128><<<dim3(QKV_DIM/128, ROWS/128), 256, 0, stream>>>(ln1o, IN_C, wqkvT, IN_C, qkv_b, nullptr, 0, qkvb, QKV_DIM, IN_C);
  k_repack_k<<<dim3(1024), 256, 0, stream>>>(qkvb, kfrag);
  k_repack_v<<<dim3(1024), 256, 0, stream>>>(qkvb, vfrag);
  k_attn<<<dim3(2048), 256, 0, stream>>>(qkvb, kfrag, vfrag, atto);
  k_gemm<1,64><<<dim3(IN_C/64, ROWS/128), 256, 0, stream>>>(atto, MERGE_K, wmergeT, MERGE_K, merge_b, x, IN_C, x2, IN_C, MERGE_K);
  k_ln2<<<dim3(ROWS/4), 256, 0, stream>>>(x2, ttb, ln2_g, ln2_b, ln2o);
  k_gemm<2,128><<<dim3(EXPAND_C/128, ROWS/128), 256, 0, stream>>>(ln2o, LN2_C, wff1T, LN2_C, ff1_b, nullptr, 0, hbuf, EXPAND_C, LN2_C);
  k_gemm<1,64><<<dim3(IN_C/64, ROWS/128), 256, 0, stream>>>(hbuf, EXPAND_C, wff2T, EXPAND_C, ff2_b, x2, IN_C, (float*)d_out, IN_C, EXPAND_C);

  (void)in_sizes; (void)n_in; (void)out_size; (void)ws_size;
}

// Round 17
// 578.352 us; speedup vs baseline: 1.1260x; 1.1260x over previous
//
#include <hip/hip_runtime.h>

#define IN_C 512
#define HEAD_C 64
#define NHEAD 8
#define TIME_C 256
#define EXPAND_C 2048
#define NB 4
#define NN 2048
#define QKV_DIM 5120   /* 64*8*2 + 512*8 */
#define ROWS (NB*NN)   /* 8192 */
#define MERGE_K (NHEAD*IN_C) /* 4096 */
#define LN2_C (IN_C+TIME_C)  /* 768 */

typedef __bf16 bf16x8 __attribute__((ext_vector_type(8)));
typedef float f32x4 __attribute__((ext_vector_type(4)));
typedef float f32x16 __attribute__((ext_vector_type(16)));
typedef unsigned int u32x4 __attribute__((ext_vector_type(4)));
typedef unsigned short u16x4v __attribute__((ext_vector_type(4)));

__device__ __forceinline__ unsigned short f2bf(float f){
  unsigned int u = __builtin_bit_cast(unsigned int, f);
  u += 0x7fffu + ((u >> 16) & 1u);
  return (unsigned short)(u >> 16);
}
__device__ __forceinline__ unsigned int cvtpk(float a, float b){
  unsigned int r;
  asm("v_cvt_pk_bf16_f32 %0, %1, %2" : "=v"(r) : "v"(a), "v"(b));
  return r;
}
__device__ __forceinline__ float vexp2(float x){   // D = 2^S0
  float r;
  asm("v_exp_f32 %0, %1" : "=v"(r) : "v"(x));
  return r;
}
__device__ __forceinline__ float bpermf(float v, int srclane){
  int r = __builtin_amdgcn_ds_bpermute(srclane<<2, __builtin_bit_cast(int, v));
  return __builtin_bit_cast(float, r);
}
// async global->LDS, 16B per lane; LDS dest is wave-uniform base + lane*16
__device__ __forceinline__ void gload16(const unsigned short* g, unsigned short* l){
  __builtin_amdgcn_global_load_lds(
      (const __attribute__((address_space(1))) void*)g,
      (__attribute__((address_space(3))) void*)l, 16, 0, 0);
}

// ---------------- batched weight cast+transpose: 4 weights in one launch ----------------
// seg0 qkv  (K=512,N=5120): 640 tiles; seg1 merge (K=4096,N=512): 512;
// seg2 ff1  (K=768,N=2048): 384;       seg3 ff2  (K=2048,N=512): 256.  total 1792.
__global__ __launch_bounds__(256) void k_transpose_w4(const float* __restrict__ W0, unsigned short* __restrict__ T0,
                                                      const float* __restrict__ W1, unsigned short* __restrict__ T1,
                                                      const float* __restrict__ W2, unsigned short* __restrict__ T2,
                                                      const float* __restrict__ W3, unsigned short* __restrict__ T3){
  __shared__ unsigned short tile[64*72];
  int bi = blockIdx.x;
  const float* W; unsigned short* Wt; int K, N, ti;
  if (bi < 640)      { W=W0; Wt=T0; K=IN_C;     N=QKV_DIM;  ti=bi; }
  else if (bi < 1152){ W=W1; Wt=T1; K=MERGE_K;  N=IN_C;     ti=bi-640; }
  else if (bi < 1536){ W=W2; Wt=T2; K=LN2_C;    N=EXPAND_C; ti=bi-1152; }
  else               { W=W3; Wt=T3; K=EXPAND_C; N=IN_C;     ti=bi-1536; }
  int nx = N>>6;
  int nb = (ti % nx)<<6, kb = (ti / nx)<<6;
  int t = threadIdx.x;
  {
    int kr = t>>2, nc = (t&3)<<4;
    const float* src = W + (size_t)(kb+kr)*N + nb + nc;
    alignas(16) unsigned short tmp[16];
    #pragma unroll
    for (int j=0;j<16;j+=4){
      float4 v = *(const float4*)(src + j);
      tmp[j+0]=f2bf(v.x); tmp[j+1]=f2bf(v.y); tmp[j+2]=f2bf(v.z); tmp[j+3]=f2bf(v.w);
    }
    *(bf16x8*)&tile[kr*72 + nc]     = *(bf16x8*)&tmp[0];
    *(bf16x8*)&tile[kr*72 + nc + 8] = *(bf16x8*)&tmp[8];
  }
  __syncthreads();
  {
    int nr = t>>2, kc = (t&3)<<4;
    alignas(16) unsigned short ov[16];
    #pragma unroll
    for (int i=0;i<16;i++) ov[i] = tile[(kc+i)*72 + nr];
    unsigned short* dst = Wt + (size_t)(nb+nr)*K + kb + kc;
    *(bf16x8*)dst     = *(bf16x8*)&ov[0];
    *(bf16x8*)(dst+8) = *(bf16x8*)&ov[8];
  }
}

// ---------------- combined K+V repack (one launch, grid 2048) ----------------
// blocks [0,1024): K repack with swap23 key permutation (lane-local attn P-pack);
// blocks [1024,2048): V repack to 32x32 B-frag-linear layout. Logic identical to r15.
__global__ __launch_bounds__(256) void k_repack_kv(const unsigned short* __restrict__ qkv,
                                                   unsigned short* __restrict__ Kf,
                                                   unsigned short* __restrict__ Vf){
  __shared__ unsigned short tile[64*136];
  int bi = blockIdx.x;
  int t = threadIdx.x, l = t&63, w = t>>6;
  if (bi < 1024){
    int j = bi;
    int kb64 = j&31, bh = j>>5;
    int b = bh>>3, hh = bh&7;
    {
      int key = t>>2, sc = t&3;
      const unsigned short* src = qkv + (size_t)(b*NN + kb64*64 + key)*QKV_DIM + IN_C + hh*HEAD_C;
      *(bf16x8*)&tile[key*72 + sc*8]     = *(const bf16x8*)(src + sc*8);
      *(bf16x8*)&tile[key*72 + (sc+4)*8] = *(const bf16x8*)(src + (sc+4)*8);
    }
    __syncthreads();
    int kb32l = w&1, kk0 = w>>1;
    int lkey = l&31;
    int pk = (lkey & ~12) | ((lkey&4)<<1) | ((lkey&8)>>1);   // swap bits 2<->3
    #pragma unroll
    for (int i=0;i<2;i++){
      int kk = kk0 + i*2;
      alignas(16) unsigned short ov[8];
      #pragma unroll
      for (int jj=0;jj<8;jj++)
        ov[jj] = tile[(kb32l*32 + pk)*72 + kk*16 + (l>>5)*8 + jj];
      size_t dst = (((size_t)(bh*64 + kb64*2 + kb32l))*4 + kk)*512 + l*8;
      *(bf16x8*)(Kf + dst) = *(bf16x8*)ov;
    }
  } else {
    int j = bi - 1024;
    int kb64 = j&31, bh = j>>5;
    int b = bh>>3, hh = bh&7;
    int key = t>>2, sc = t&3;
    const unsigned short* srow = qkv + (size_t)(b*NN + kb64*64 + key)*QKV_DIM + 2*IN_C + hh*IN_C;
    for (int p=0;p<4;p++){
      #pragma unroll
      for (int i=0;i<4;i++){
        int ch = sc + i*4;
        *(bf16x8*)&tile[key*136 + ch*8] = *(const bf16x8*)(srow + p*128 + ch*8);
      }
      __syncthreads();
      #pragma unroll
      for (int dbl=0;dbl<4;dbl++){
        alignas(16) unsigned short ov[8];
        #pragma unroll
        for (int jj=0;jj<8;jj++)
          ov[jj] = tile[(w*16 + (l>>5)*8 + jj)*136 + dbl*32 + (l&31)];
        size_t dst = (((size_t)(bh*128 + kb64*4 + w))*16 + p*4 + dbl)*512 + l*8;
        *(bf16x8*)(Vf + dst) = *(bf16x8*)ov;
      }
      __syncthreads();
    }
  }
}

// ---------------- LN1: x[8192][512] f32 -> bf16 ----------------
__global__ __launch_bounds__(256) void k_ln1(const float* __restrict__ x,
                                             const float* __restrict__ g,
                                             const float* __restrict__ bta,
                                             unsigned short* __restrict__ out){
  int row = (blockIdx.x<<2) + (threadIdx.x>>6);
  int l = threadIdx.x&63;
  const float* px = x + (size_t)row*IN_C + l*8;
  alignas(16) float v[8];
  *(float4*)&v[0] = *(const float4*)px;
  *(float4*)&v[4] = *(const float4*)(px+4);
  float s=0.f, sq=0.f;
  #pragma unroll
  for (int j=0;j<8;j++){ s+=v[j]; sq+=v[j]*v[j]; }
  #pragma unroll
  for (int d=32; d>0; d>>=1){ s += __shfl_xor(s,d); sq += __shfl_xor(sq,d); }
  float mu = s*(1.f/IN_C);
  float var = sq*(1.f/IN_C) - mu*mu;
  float rstd = rsqrtf(var + 1e-5f);
  alignas(16) unsigned short o[8];
  #pragma unroll
  for (int j=0;j<8;j++){
    int c = l*8+j;
    o[j] = f2bf((v[j]-mu)*rstd*g[c] + bta[c]);
  }
  *(bf16x8*)(out + (size_t)row*IN_C + l*8) = *(bf16x8*)o;
}

// ---------------- time MLP: tt[b][j] = t[b] @ W + b ----------------
__global__ __launch_bounds__(256) void k_time(const float* __restrict__ t,
                                              const float* __restrict__ W,
                                              const float* __restrict__ bias,
                                              float* __restrict__ tt){
  int b = blockIdx.x, j = threadIdx.x;
  float acc = bias[j];
  const float* tr = t + b*TIME_C;
  #pragma unroll 4
  for (int c=0;c<TIME_C;c++) acc = fmaf(tr[c], W[c*TIME_C + j], acc);
  tt[b*TIME_C + j] = acc;
}

// ---------------- LN2 over concat(x2[512], tt[256]) -> bf16[8192][768], vectorized ----------------
__global__ __launch_bounds__(256) void k_ln2(const float* __restrict__ x2,
                                             const float* __restrict__ tt,
                                             const float* __restrict__ g,
                                             const float* __restrict__ bta,
                                             unsigned short* __restrict__ out){
  int row = (blockIdx.x<<2) + (threadIdx.x>>6);
  int l = threadIdx.x&63;
  int bi = row>>11;
  int c0 = l*12;
  alignas(16) float v[12], gg[12], bb[12];
  #pragma unroll
  for (int q=0;q<3;q++){
    int c = c0 + q*4;
    const float* src = (c < IN_C) ? &x2[(size_t)row*IN_C + c] : &tt[bi*TIME_C + c - IN_C];
    *(float4*)&v[q*4]  = *(const float4*)src;
    *(float4*)&gg[q*4] = *(const float4*)&g[c];
    *(float4*)&bb[q*4] = *(const float4*)&bta[c];
  }
  float s=0.f, sq=0.f;
  #pragma unroll
  for (int j=0;j<12;j++){ s+=v[j]; sq+=v[j]*v[j]; }
  #pragma unroll
  for (int d=32; d>0; d>>=1){ s += __shfl_xor(s,d); sq += __shfl_xor(sq,d); }
  float mu = s*(1.f/LN2_C);
  float var = sq*(1.f/LN2_C) - mu*mu;
  float rstd = rsqrtf(var + 1e-5f);
  alignas(8) unsigned short ov[12];
  #pragma unroll
  for (int j=0;j<12;j++)
    ov[j] = f2bf((v[j]-mu)*rstd*gg[j] + bb[j]);
  unsigned short* po = out + (size_t)row*LN2_C + c0;
  *(u16x4v*)&po[0] = *(u16x4v*)&ov[0];
  *(u16x4v*)&po[4] = *(u16x4v*)&ov[4];
  *(u16x4v*)&po[8] = *(u16x4v*)&ov[8];
}

// ---------------- GEMM (m97 structure): global_load_lds staging, BK=64, BN templated,
// XCD-chunked block swizzle (T1).
template<int EPI, int BN>
__global__ __launch_bounds__(256) void k_gemm(const unsigned short* __restrict__ A, int lda,
                                              const unsigned short* __restrict__ Bt, int ldb,
                                              const float* __restrict__ bias,
                                              const float* __restrict__ res, int ldres,
                                              void* __restrict__ Cp, int ldc, int K){
  constexpr int NI = BN/32;                 // acc cols per wave
  __shared__ unsigned short sA[128*64];
  __shared__ unsigned short sB[BN*64];
  int t = threadIdx.x;
  int l = t&63, w = t>>6;
  // bijective XCD-chunked swizzle (nwg % 8 == 0 for all our launches)
  int nxb = gridDim.x;
  int bid = blockIdx.x + nxb*blockIdx.y;
  int cpx = (nxb*gridDim.y) >> 3;
  int sb  = (bid&7)*cpx + (bid>>3);
  int bx  = sb % nxb, by = sb / nxb;
  int m0 = by<<7, n0 = bx*BN;
  int wr = (w>>1)<<6, wc = (w&1)*(BN/2);
  int lm = l&15, kq = (l>>4)<<3;
  f32x4 acc[4][NI] = {};
  int srow = l>>3, scol = (l&7)<<3;
  const unsigned short* pA = A + (size_t)m0*lda;
  const unsigned short* pB = Bt + (size_t)n0*ldb;
  for (int k0=0; k0<K; k0+=64){
    #pragma unroll
    for (int i=0;i<4;i++){
      int c = w*4 + i;
      gload16(pA + (size_t)(c*8 + srow)*lda + k0 + scol, &sA[c*512]);
    }
    #pragma unroll
    for (int i=0;i<BN/32;i++){
      int c = w*(BN/32) + i;
      gload16(pB + (size_t)(c*8 + srow)*ldb + k0 + scol, &sB[c*512]);
    }
    __syncthreads();                       // vmcnt drained -> tiles ready
    bf16x8 af[2][4], bfv[2][NI];
    #pragma unroll
    for (int kk=0;kk<2;kk++){
      #pragma unroll
      for (int i=0;i<4;i++)
        af[kk][i]  = *(const bf16x8*)&sA[(wr + i*16 + lm)*64 + kk*32 + kq];
      #pragma unroll
      for (int i=0;i<NI;i++)
        bfv[kk][i] = *(const bf16x8*)&sB[(wc + i*16 + lm)*64 + kk*32 + kq];
    }
    #pragma unroll
    for (int kk=0;kk<2;kk++)
      #pragma unroll
      for (int mi=0;mi<4;mi++)
        #pragma unroll
        for (int ni=0;ni<NI;ni++)
          acc[mi][ni] = __builtin_amdgcn_mfma_f32_16x16x32_bf16(af[kk][mi], bfv[kk][ni], acc[mi][ni], 0,0,0);
    __syncthreads();                       // all reads done before next stage
  }
  int lr4 = (l>>4)<<2;
  #pragma unroll
  for (int mi=0;mi<4;mi++){
    int row0 = m0 + wr + mi*16 + lr4;
    #pragma unroll
    for (int ni=0;ni<NI;ni++){
      int col = n0 + wc + ni*16 + lm;
      float bi = bias[col];
      #pragma unroll
      for (int r=0;r<4;r++){
        float v = acc[mi][ni][r] + bi;
        int row = row0 + r;
        if (EPI==1){
          v += res[(size_t)row*ldres + col];
          ((float*)Cp)[(size_t)row*ldc + col] = v;
        } else if (EPI==2){
          v = 0.5f*v*(1.f + erff(v*0.70710678118f));
          ((unsigned short*)Cp)[(size_t)row*ldc + col] = f2bf(v);
        } else {
          ((unsigned short*)Cp)[(size_t)row*ldc + col] = f2bf(v);
        }
      }
    }
  }
}

// ---------------- flash attention v13 (proven 251us): key-permuted Kf, no cross-lane P-pack ----
// 2048 blocks x 256 thr (4 waves). Wave = (bh, 32 q-rows, 128 d-cols).
// Kf keys swap23-permuted -> pf0 = cvtpk(pv[0..7]), pf1 = cvtpk(pv[8..15]) lane-local.
// Vf natural order. No barriers, no LDS, no setprio.
__global__ __launch_bounds__(256, 4) void k_attn(const unsigned short* __restrict__ qkv,
                                                 const unsigned short* __restrict__ Kf,
                                                 const unsigned short* __restrict__ Vf,
                                                 unsigned short* __restrict__ out){
  int j = blockIdx.x;
  int xcd = j&7;
  int rest = j>>3;                 // 0..255
  int bh = xcd + ((rest>>6)<<3);   // 4 bh-groups of 8 per XCD
  int inner = rest&63;
  int qb = inner>>2, dh = inner&3;
  int b = bh>>3, hh = bh&7;
  int t = threadIdx.x, l = t&63, w = t>>6;
  int q0 = qb*128 + w*32;
  int lq = l&31, half = l>>5;

  // Q fragments (B operand), pre-scaled so exp2 applies directly to S
  bf16x8 qf[4];
  #pragma unroll
  for (int kk=0;kk<4;kk++){
    bf16x8 raw = *(const bf16x8*)(qkv + (size_t)(b*NN + q0 + lq)*QKV_DIM + hh*HEAD_C + kk*16 + half*8);
    u32x4 u = __builtin_bit_cast(u32x4, raw);
    u32x4 rr;
    #pragma unroll
    for (int jj=0;jj<4;jj++){
      float lo = __builtin_bit_cast(float, (u[jj]&0xffffu)<<16);
      float hi = __builtin_bit_cast(float, u[jj]&0xffff0000u);
      rr[jj] = cvtpk(lo*0.18033688f, hi*0.18033688f);   // 0.125*log2(e)
    }
    qf[kk] = __builtin_bit_cast(bf16x8, rr);
  }

  f32x16 o[4] = {};                // D[q][d]: col=lane&31=d, row(q)=(r&3)+8*(r>>2)+4*half
  float l_ = 0.f;                  // per-lane: sum over THIS half's 16 keys/body

  const unsigned short* Kbase = Kf + (size_t)bh*64*2048 + l*8;
  const unsigned short* Vbase = Vf + ((size_t)bh*128*16 + dh*4)*512 + l*8;

  for (int c=0;c<64;c++){
    const unsigned short* kp = Kbase + (size_t)c*2048;
    bf16x8 kf0 = *(const bf16x8*)(kp);
    bf16x8 kf1 = *(const bf16x8*)(kp + 512);
    bf16x8 kf2 = *(const bf16x8*)(kp + 1024);
    bf16x8 kf3 = *(const bf16x8*)(kp + 1536);

    // QK^T swapped: D[perm-key][q]; lane holds 16 keys (its half) for q = q0+lq
    f32x16 s = {};
    s = __builtin_amdgcn_mfma_f32_32x32x16_bf16(kf0, qf[0], s, 0,0,0);
    s = __builtin_amdgcn_mfma_f32_32x32x16_bf16(kf1, qf[1], s, 0,0,0);
    s = __builtin_amdgcn_mfma_f32_32x32x16_bf16(kf2, qf[2], s, 0,0,0);
    s = __builtin_amdgcn_mfma_f32_32x32x16_bf16(kf3, qf[3], s, 0,0,0);

    float pv[16]; float ps = 0.f;
    #pragma unroll
    for (int r=0;r<16;r++){
      pv[r] = vexp2(s[r]);        // S already scaled
      ps += pv[r];
    }
    l_ += ps;                      // cross-half reduce deferred to epilogue

    // pack P into A-frags: keys already lane-local thanks to swap23 K layout
    bf16x8 pf0 = __builtin_bit_cast(bf16x8, (u32x4){ cvtpk(pv[0],pv[1]),  cvtpk(pv[2],pv[3]),
                                                     cvtpk(pv[4],pv[5]),  cvtpk(pv[6],pv[7]) });
    bf16x8 pf1 = __builtin_bit_cast(bf16x8, (u32x4){ cvtpk(pv[8],pv[9]),  cvtpk(pv[10],pv[11]),
                                                     cvtpk(pv[12],pv[13]),cvtpk(pv[14],pv[15]) });

    // PV in two half-phases (16 V regs live at a time)
    const unsigned short* vp = Vbase + (size_t)c*16384;
    {
      bf16x8 v0 = *(const bf16x8*)(vp);
      bf16x8 v1 = *(const bf16x8*)(vp + 512);
      bf16x8 v2 = *(const bf16x8*)(vp + 1024);
      bf16x8 v3 = *(const bf16x8*)(vp + 1536);
      o[0] = __builtin_amdgcn_mfma_f32_32x32x16_bf16(pf0, v0, o[0], 0,0,0);
      o[1] = __builtin_amdgcn_mfma_f32_32x32x16_bf16(pf0, v1, o[1], 0,0,0);
      o[2] = __builtin_amdgcn_mfma_f32_32x32x16_bf16(pf0, v2, o[2], 0,0,0);
      o[3] = __builtin_amdgcn_mfma_f32_32x32x16_bf16(pf0, v3, o[3], 0,0,0);
    }
    {
      bf16x8 v0 = *(const bf16x8*)(vp + 8192);
      bf16x8 v1 = *(const bf16x8*)(vp + 8704);
      bf16x8 v2 = *(const bf16x8*)(vp + 9216);
      bf16x8 v3 = *(const bf16x8*)(vp + 9728);
      o[0] = __builtin_amdgcn_mfma_f32_32x32x16_bf16(pf1, v0, o[0], 0,0,0);
      o[1] = __builtin_amdgcn_mfma_f32_32x32x16_bf16(pf1, v1, o[1], 0,0,0);
      o[2] = __builtin_amdgcn_mfma_f32_32x32x16_bf16(pf1, v2, o[2], 0,0,0);
      o[3] = __builtin_amdgcn_mfma_f32_32x32x16_bf16(pf1, v3, o[3], 0,0,0);
    }
  }

  l_ += __shfl_xor(l_, 32);        // complete the row sum (halves hold disjoint key sets)
  float invl = 1.f / l_;
  #pragma unroll
  for (int r=0;r<16;r++){
    int qr = (r&3) + 8*(r>>2) + 4*half;
    float il = bpermf(invl, qr);
    size_t row = (size_t)(b*NN + q0 + qr);
    #pragma unroll
    for (int dn=0;dn<4;dn++){
      int col = hh*IN_C + dh*128 + dn*32 + lq;
      out[row*MERGE_K + col] = f2bf(o[dn][r]*il);
    }
  }
}

extern "C" void kernel_launch(void* const* d_in, const int* in_sizes, int n_in,
                              void* d_out, int out_size, void* d_ws, size_t ws_size,
                              hipStream_t stream){
  const float* x       = (const float*)d_in[0];
  const float* tin     = (const float*)d_in[1];
  const float* ln1_g   = (const float*)d_in[2];
  const float* ln1_b   = (const float*)d_in[3];
  const float* qkv_w   = (const float*)d_in[4];
  const float* qkv_b   = (const float*)d_in[5];
  const float* merge_w = (const float*)d_in[6];
  const float* merge_b = (const float*)d_in[7];
  const float* time_w  = (const float*)d_in[8];
  const float* time_b  = (const float*)d_in[9];
  const float* ln2_g   = (const float*)d_in[10];
  const float* ln2_b   = (const float*)d_in[11];
  const float* ff1_w   = (const float*)d_in[12];
  const float* ff1_b   = (const float*)d_in[13];
  const float* ff2_w   = (const float*)d_in[14];
  const float* ff2_b   = (const float*)d_in[15];

  char* ws = (char*)d_ws;
  size_t off = 0;
  auto alloc = [&](size_t bytes)->void*{ void* p = ws + off; off += (bytes + 255) & ~(size_t)255; return p; };
  unsigned short* wqkvT   = (unsigned short*)alloc((size_t)QKV_DIM*IN_C*2);
  unsigned short* wmergeT = (unsigned short*)alloc((size_t)IN_C*MERGE_K*2);
  unsigned short* wff1T   = (unsigned short*)alloc((size_t)EXPAND_C*LN2_C*2);
  unsigned short* wff2T   = (unsigned short*)alloc((size_t)IN_C*EXPAND_C*2);
  float*          ttb     = (float*)alloc((size_t)NB*TIME_C*4);
  unsigned short* ln1o    = (unsigned short*)alloc((size_t)ROWS*IN_C*2);
  unsigned short* qkvb    = (unsigned short*)alloc((size_t)ROWS*QKV_DIM*2);
  unsigned short* kfrag   = (unsigned short*)alloc((size_t)32*64*4*64*8*2);      // 8 MB
  unsigned short* vfrag   = (unsigned short*)alloc((size_t)32*128*16*64*8*2);    // 64 MB
  unsigned short* atto    = (unsigned short*)alloc((size_t)ROWS*MERGE_K*2);
  float*          x2      = (float*)alloc((size_t)ROWS*IN_C*4);
  // aliases over dead buffers (lifetimes verified):
  unsigned short* ln2o = vfrag; // vfrag dead after k_attn
  unsigned short* hbuf = qkvb;  // qkvb dead after k_attn

  k_transpose_w4<<<dim3(1792), 256, 0, stream>>>(qkv_w, wqkvT, merge_w, wmergeT,
                                                 ff1_w, wff1T, ff2_w, wff2T);
  k_time<<<dim3(NB), 256, 0, stream>>>(tin, time_w, time_b, ttb);
  k_ln1<<<dim3(ROWS/4), 256, 0, stream>>>(x, ln1_g, ln1_b, ln1o);

  k_gemm<0,128><<<dim3(QKV_DIM/128, ROWS/128), 256, 0, stream>>>(ln1o, IN_C, wqkvT, IN_C, qkv_b, nullptr, 0, qkvb, QKV_DIM, IN_C);
  k_repack_kv<<<dim3(2048), 256, 0, stream>>>(qkvb, kfrag, vfrag);
  k_attn<<<dim3(2048), 256, 0, stream>>>(qkvb, kfrag, vfrag, atto);
  k_gemm<1,64><<<dim3(IN_C/64, ROWS/128), 256, 0, stream>>>(atto, MERGE_K, wmergeT, MERGE_K, merge_b, x, IN_C, x2, IN_C, MERGE_K);
  k_ln2<<<dim3(ROWS/4), 256, 0, stream>>>(x2, ttb, ln2_g, ln2_b, ln2o);
  k_gemm<2,128><<<dim3(EXPAND_C/128, ROWS/128), 256, 0, stream>>>(ln2o, LN2_C, wff1T, LN2_C, ff1_b, nullptr, 0, hbuf, EXPAND_C, LN2_C);
  k_gemm<1,64><<<dim3(IN_C/64, ROWS/128), 256, 0, stream>>>(hbuf, EXPAND_C, wff2T, EXPAND_C, ff2_b, x2, IN_C, (float*)d_out, IN_C, EXPAND_C);

  (void)in_sizes; (void)n_in; (void)out_size; (void)ws_size;
}